// Round 1
// baseline (667.931 us; speedup 1.0000x reference)
//
#include <hip/hip_runtime.h>
#include <math.h>

namespace {
constexpr int B = 2;
constexpr int N = 16384;
constexpr int M = 4096;
constexpr int K = 11;
constexpr int BLOCK = 128;   // 2 waves/block; grid = B*N/BLOCK = 256 blocks -> 1 block per CU
}

__global__ __launch_bounds__(BLOCK) void voroloss_kernel(
    const float* __restrict__ points,    // [B, N, 3]
    const float* __restrict__ spoints,   // [B, M, 3]
    float* __restrict__ out)             // [B, N]
{
  // Spoints of this batch staged as (x, y, z, |s|^2). 64 KiB LDS.
  __shared__ float4 s4[M];

  const int blocks_per_batch = N / BLOCK;
  const int b = blockIdx.x / blocks_per_batch;
  const int tile = blockIdx.x % blocks_per_batch;
  const int n = tile * BLOCK + (int)threadIdx.x;

  const float* sp = spoints + (size_t)b * M * 3;
  for (int j = threadIdx.x; j < M; j += BLOCK) {
    float x = sp[j * 3 + 0];
    float y = sp[j * 3 + 1];
    float z = sp[j * 3 + 2];
    s4[j] = make_float4(x, y, z, x * x + y * y + z * z);
  }
  __syncthreads();

  const float px = points[((size_t)b * N + n) * 3 + 0];
  const float py = points[((size_t)b * N + n) * 3 + 1];
  const float pz = points[((size_t)b * N + n) * 3 + 2];
  const float pp = px * px + py * py + pz * pz;

  // Top-K smallest distances, sorted ascending, in registers.
  // Fully unrolled compare-swap insertion: no dynamic indexing -> no scratch.
  float bd[K];
  int bi[K];
#pragma unroll
  for (int t = 0; t < K; ++t) { bd[t] = INFINITY; bi[t] = 0; }

  for (int j = 0; j < M; ++j) {
    float4 s = s4[j];   // wave-uniform address -> LDS broadcast
    float dot = px * s.x + py * s.y + pz * s.z;
    float d2 = pp + s.w - 2.0f * dot;   // same algebra as reference
    if (d2 < bd[K - 1]) {               // rare after warm-up
      float d = d2;
      int id = j;
#pragma unroll
      for (int t = 0; t < K; ++t) {
        bool sw = d < bd[t];            // strict <: lower index wins ties (top_k semantics)
        float td = sw ? bd[t] : d;
        int ti = sw ? bi[t] : id;
        bd[t] = sw ? d : bd[t];
        bi[t] = sw ? id : bi[t];
        d = td;
        id = ti;
      }
    }
  }

  // Epilogue: nearest = bi[0] = inside_cell; edges to neighbors 1..10.
  float4 c = s4[bi[0]];
  const float vx = px - c.x, vy = py - c.y, vz = pz - c.z;
  float best = INFINITY;
#pragma unroll
  for (int t = 1; t < K; ++t) {
    float4 s = s4[bi[t]];
    float ex = s.x - c.x, ey = s.y - c.y, ez = s.z - c.z;
    float el2 = ex * ex + ey * ey + ez * ez;
    float el = sqrtf(el2);
    float dotv = vx * ex + vy * ey + vz * ez;
    float vl = dotv / el;
    float diff = vl - 0.5f * el;
    best = fminf(best, diff * diff);
  }
  out[(size_t)b * N + n] = best;
}

extern "C" void kernel_launch(void* const* d_in, const int* in_sizes, int n_in,
                              void* d_out, int out_size, void* d_ws, size_t ws_size,
                              hipStream_t stream) {
  const float* points = (const float*)d_in[0];
  const float* spoints = (const float*)d_in[1];
  float* out = (float*)d_out;
  (void)in_sizes; (void)n_in; (void)out_size; (void)d_ws; (void)ws_size;
  voroloss_kernel<<<dim3(B * (N / BLOCK)), dim3(BLOCK), 0, stream>>>(points, spoints, out);
}

// Round 2
// 359.886 us; speedup vs baseline: 1.8560x; 1.8560x over previous
//
#include <hip/hip_runtime.h>
#include <math.h>

namespace {
constexpr int B = 2;
constexpr int N = 16384;
constexpr int M = 4096;
constexpr int K = 11;
constexpr int T = 2;            // threads per query (M split in halves)
constexpr int BLOCK = 256;      // 128 queries/block, 4 waves/block; grid=256 -> 1 block/CU
constexpr int QPB = BLOCK / T;  // queries per block
constexpr int S = M / T;        // spoints scanned per thread
}

__global__ __launch_bounds__(BLOCK) void voroloss_kernel(
    const float* __restrict__ points,    // [B, N, 3]
    const float* __restrict__ spoints,   // [B, M, 3]
    float* __restrict__ out)             // [B, N]
{
  // Batch's spoints as (x, y, z, |s|^2). 64 KiB LDS.
  __shared__ float4 s4[M];

  const int blocks_per_batch = N / QPB;
  const int b = blockIdx.x / blocks_per_batch;
  const int tile = blockIdx.x % blocks_per_batch;
  const int tid = (int)threadIdx.x;
  const int q = tid >> 1;       // local query id (pair = adjacent lanes)
  const int h = tid & 1;        // which half of M this thread scans
  const int n = tile * QPB + q;

  const float* sp = spoints + (size_t)b * M * 3;
  for (int j = tid; j < M; j += BLOCK) {
    float x = sp[j * 3 + 0], y = sp[j * 3 + 1], z = sp[j * 3 + 2];
    s4[j] = make_float4(x, y, z, x * x + y * y + z * z);
  }
  __syncthreads();

  const float px = points[((size_t)b * N + n) * 3 + 0];
  const float py = points[((size_t)b * N + n) * 3 + 1];
  const float pz = points[((size_t)b * N + n) * 3 + 2];
  const float pp = px * px + py * py + pz * pz;

  // ---- Pass 1: top-K smallest d2 over this thread's half (values only), + argmin idx.
  float bd[K];
#pragma unroll
  for (int t = 0; t < K; ++t) bd[t] = INFINITY;
  int bidx = 0;

  const int base = h * S;
  for (int i0 = 0; i0 < S; i0 += 8) {
    float d2v[8];
#pragma unroll
    for (int c = 0; c < 8; ++c) {
      float4 s = s4[base + i0 + c];   // 2 distinct addrs/wave -> free broadcast
      float dot = px * s.x;
      dot = fmaf(py, s.y, dot);
      dot = fmaf(pz, s.z, dot);
      d2v[c] = fmaf(-2.0f, dot, pp + s.w);
    }
    float m01 = fminf(d2v[0], d2v[1]), m23 = fminf(d2v[2], d2v[3]);
    float m45 = fminf(d2v[4], d2v[5]), m67 = fminf(d2v[6], d2v[7]);
    float m = fminf(fminf(m01, m23), fminf(m45, m67));
    if (m < bd[K - 1]) {
#pragma unroll
      for (int c = 0; c < 8; ++c) {
        float d = d2v[c];
        if (d < bd[K - 1]) {
          bool ismin = d < bd[0];
#pragma unroll
          for (int t = 0; t < K; ++t) {   // values-only sorted insert (min/max chain)
            float lo = fminf(bd[t], d);
            d = fmaxf(bd[t], d);
            bd[t] = lo;
          }
          bidx = ismin ? (base + i0 + c) : bidx;
        }
      }
    }
  }

  // ---- Pair merge via shuffle: 11th-smallest of union = max_t min(A[t], B[K-1-t]).
  float bd10 = -INFINITY;
#pragma unroll
  for (int t = 0; t < K; ++t) {
    float ob = __shfl_xor(bd[K - 1 - t], 1);
    bd10 = fmaxf(bd10, fminf(bd[t], ob));
  }
  // Nearest (inside cell): min across pair, lower index wins exact ties.
  float omin = __shfl_xor(bd[0], 1);
  int obidx = __shfl_xor(bidx, 1);
  bool takeo = (omin < bd[0]) || (omin == bd[0] && obidx < bidx);
  int cidx = takeo ? obidx : bidx;

  float4 cc = s4[cidx];
  const float vx = px - cc.x, vy = py - cc.y, vz = pz - cc.z;

  // ---- Pass 2: rescan own half; points with d2 <= bd10 (excluding center) are the
  // 10 neighbors. sq = (dot(v,e)/|e| - |e|/2)^2 = (dot(v,e) - |e|^2/2)^2 / |e|^2.
  float best = INFINITY;
  for (int i0 = 0; i0 < S; i0 += 8) {
    float4 sv[8];
    float d2v[8];
#pragma unroll
    for (int c = 0; c < 8; ++c) {
      sv[c] = s4[base + i0 + c];
      float dot = px * sv[c].x;
      dot = fmaf(py, sv[c].y, dot);
      dot = fmaf(pz, sv[c].z, dot);
      d2v[c] = fmaf(-2.0f, dot, pp + sv[c].w);
    }
    float m01 = fminf(d2v[0], d2v[1]), m23 = fminf(d2v[2], d2v[3]);
    float m45 = fminf(d2v[4], d2v[5]), m67 = fminf(d2v[6], d2v[7]);
    float m = fminf(fminf(m01, m23), fminf(m45, m67));
    if (m <= bd10) {
#pragma unroll
      for (int c = 0; c < 8; ++c) {
        int j = base + i0 + c;
        if (d2v[c] <= bd10 && j != cidx) {
          float ex = sv[c].x - cc.x, ey = sv[c].y - cc.y, ez = sv[c].z - cc.z;
          float el2 = ex * ex;
          el2 = fmaf(ey, ey, el2);
          el2 = fmaf(ez, ez, el2);
          float dotv = vx * ex;
          dotv = fmaf(vy, ey, dotv);
          dotv = fmaf(vz, ez, dotv);
          float tt = fmaf(-0.5f, el2, dotv);
          best = fminf(best, tt * tt / el2);
        }
      }
    }
  }
  float obest = __shfl_xor(best, 1);
  best = fminf(best, obest);
  if (h == 0) out[(size_t)b * N + n] = best;
}

extern "C" void kernel_launch(void* const* d_in, const int* in_sizes, int n_in,
                              void* d_out, int out_size, void* d_ws, size_t ws_size,
                              hipStream_t stream) {
  const float* points = (const float*)d_in[0];
  const float* spoints = (const float*)d_in[1];
  float* out = (float*)d_out;
  (void)in_sizes; (void)n_in; (void)out_size; (void)d_ws; (void)ws_size;
  voroloss_kernel<<<dim3(B * (N / QPB)), dim3(BLOCK), 0, stream>>>(points, spoints, out);
}

// Round 4
// 245.032 us; speedup vs baseline: 2.7259x; 1.4687x over previous
//
#include <hip/hip_runtime.h>
#include <math.h>

namespace {
constexpr int B = 2;
constexpr int N = 16384;
constexpr int M = 4096;
constexpr int K = 11;
constexpr int TQ = 8;            // lanes per query
constexpr int BLOCK = 512;       // 8 waves/block; 2 blocks/CU (LDS-limited) -> 16 waves/CU
constexpr int QPB = BLOCK / TQ;  // 64 queries per block
constexpr int S = M / TQ;        // 512 candidates per lane
}

// DESCENDING compare-exchange on L[] (larger value to lower index).
// Lang's arbitrary-n bitonic merge with descending CEs is valid on
// MOUNTAIN-shaped (asc-then-desc) bitonic input; min(asc A, desc B-rev)
// is always a mountain. (Ascending CEs would need valley input -- that
// was the R3 bug.)
#define CED(a, b) { float hi_ = fmaxf(L[a], L[b]); L[b] = fminf(L[a], L[b]); L[a] = hi_; }

__global__ __launch_bounds__(BLOCK, 4) void voroloss_kernel(
    const float* __restrict__ points,    // [B, N, 3]
    const float* __restrict__ spoints,   // [B, M, 3]
    float* __restrict__ out)             // [B, N]
{
  // Batch's spoints as (x, y, z, |s|^2). 64 KiB LDS.
  __shared__ float4 s4[M];

  const int blocks_per_batch = N / QPB;
  const int b = blockIdx.x / blocks_per_batch;
  const int tile = blockIdx.x % blocks_per_batch;
  const int tid = (int)threadIdx.x;
  const int h = tid & (TQ - 1);   // lane within query group
  const int q = tid >> 3;         // local query id
  const int n = tile * QPB + q;

  const float* sp = spoints + (size_t)b * M * 3;
  for (int j = tid; j < M; j += BLOCK) {
    float x = sp[j * 3 + 0], y = sp[j * 3 + 1], z = sp[j * 3 + 2];
    s4[j] = make_float4(x, y, z, x * x + y * y + z * z);
  }
  __syncthreads();

  const float px = points[((size_t)b * N + n) * 3 + 0];
  const float py = points[((size_t)b * N + n) * 3 + 1];
  const float pz = points[((size_t)b * N + n) * 3 + 2];
  const float pp = px * px + py * py + pz * pz;

  // ---- Pass 1: per-lane top-K over strided subset j = i*TQ + h.
  // 8 lanes of a group read 8 consecutive float4s (128B, all 32 banks once);
  // the 8 groups in a wave read identical addresses -> broadcast, conflict-free.
  float bd[K];
#pragma unroll
  for (int t = 0; t < K; ++t) bd[t] = INFINITY;
  int bidx = 0;

  for (int i0 = 0; i0 < S; i0 += 8) {
    float d2v[8];
#pragma unroll
    for (int c = 0; c < 8; ++c) {
      float4 s = s4[(i0 + c) * TQ + h];
      float dot = px * s.x;
      dot = fmaf(py, s.y, dot);
      dot = fmaf(pz, s.z, dot);
      d2v[c] = fmaf(-2.0f, dot, pp + s.w);
    }
    float m01 = fminf(d2v[0], d2v[1]), m23 = fminf(d2v[2], d2v[3]);
    float m45 = fminf(d2v[4], d2v[5]), m67 = fminf(d2v[6], d2v[7]);
    float m = fminf(fminf(m01, m23), fminf(m45, m67));
    if (m < bd[K - 1]) {
#pragma unroll
      for (int c = 0; c < 8; ++c) {
        float d = d2v[c];
        if (d < bd[K - 1]) {
          bool ismin = d < bd[0];
#pragma unroll
          for (int t = 0; t < K; ++t) {   // values-only sorted insert
            float lo = fminf(bd[t], d);
            d = fmaxf(bd[t], d);
            bd[t] = lo;
          }
          bidx = ismin ? ((i0 + c) * TQ + h) : bidx;
        }
      }
    }
  }

  // ---- 8-way merge across the query group's lanes (xor 1, 2, 4).
  const float premin = bd[0];
#pragma unroll
  for (int lvl = 1; lvl <= 4; lvl <<= 1) {
    float L[K];
#pragma unroll
    for (int t = 0; t < K; ++t) {
      float ob = __shfl_xor(bd[K - 1 - t], lvl);
      L[t] = fminf(bd[t], ob);   // K smallest of union; mountain-bitonic
    }
    // descending bitonic merge network for n=11 (valid on mountain input)
    CED(0, 8); CED(1, 9); CED(2, 10);
    CED(0, 4); CED(1, 5); CED(2, 6); CED(3, 7);
    CED(0, 2); CED(1, 3); CED(4, 6); CED(5, 7);
    CED(0, 1); CED(2, 3); CED(4, 5); CED(6, 7);
    CED(8, 10); CED(8, 9);
    // L sorted descending; store back ascending (free index reversal)
#pragma unroll
    for (int t = 0; t < K; ++t) bd[t] = L[K - 1 - t];
  }
  const float gmin = bd[0];
  const float bd10 = bd[K - 1];

  // argmin index, lowest index wins ties (top_k semantics)
  int cand = (premin == gmin) ? bidx : 0x7fffffff;
#pragma unroll
  for (int lvl = 1; lvl <= 4; lvl <<= 1) {
    int oc = __shfl_xor(cand, lvl);
    cand = oc < cand ? oc : cand;
  }

  float4 cc = s4[cand];
  const float vx = px - cc.x, vy = py - cc.y, vz = pz - cc.z;

  // ---- Pass 2: rescan own subset; d2 <= bd10 (excluding center) are the 10
  // neighbors. sq = (dot(v,e) - |e|^2/2)^2 / |e|^2.
  float best = INFINITY;
  for (int i0 = 0; i0 < S; i0 += 8) {
    float4 sv[8];
    float d2v[8];
#pragma unroll
    for (int c = 0; c < 8; ++c) {
      sv[c] = s4[(i0 + c) * TQ + h];
      float dot = px * sv[c].x;
      dot = fmaf(py, sv[c].y, dot);
      dot = fmaf(pz, sv[c].z, dot);
      d2v[c] = fmaf(-2.0f, dot, pp + sv[c].w);
    }
    float m01 = fminf(d2v[0], d2v[1]), m23 = fminf(d2v[2], d2v[3]);
    float m45 = fminf(d2v[4], d2v[5]), m67 = fminf(d2v[6], d2v[7]);
    float m = fminf(fminf(m01, m23), fminf(m45, m67));
    if (m <= bd10) {
#pragma unroll
      for (int c = 0; c < 8; ++c) {
        int j = (i0 + c) * TQ + h;
        if (d2v[c] <= bd10 && j != cand) {
          float ex = sv[c].x - cc.x, ey = sv[c].y - cc.y, ez = sv[c].z - cc.z;
          float el2 = ex * ex;
          el2 = fmaf(ey, ey, el2);
          el2 = fmaf(ez, ez, el2);
          float dotv = vx * ex;
          dotv = fmaf(vy, ey, dotv);
          dotv = fmaf(vz, ez, dotv);
          float tt = fmaf(-0.5f, el2, dotv);
          best = fminf(best, tt * tt / el2);
        }
      }
    }
  }
#pragma unroll
  for (int lvl = 1; lvl <= 4; lvl <<= 1) {
    best = fminf(best, __shfl_xor(best, lvl));
  }
  if (h == 0) out[(size_t)b * N + n] = best;
}

extern "C" void kernel_launch(void* const* d_in, const int* in_sizes, int n_in,
                              void* d_out, int out_size, void* d_ws, size_t ws_size,
                              hipStream_t stream) {
  const float* points = (const float*)d_in[0];
  const float* spoints = (const float*)d_in[1];
  float* out = (float*)d_out;
  (void)in_sizes; (void)n_in; (void)out_size; (void)d_ws; (void)ws_size;
  voroloss_kernel<<<dim3(B * (N / QPB)), dim3(BLOCK), 0, stream>>>(points, spoints, out);
}

// Round 5
// 164.945 us; speedup vs baseline: 4.0494x; 1.4855x over previous
//
#include <hip/hip_runtime.h>
#include <math.h>

namespace {
constexpr int B = 2;
constexpr int N = 16384;
constexpr int M = 4096;
constexpr int K = 11;
constexpr int TQ = 8;               // lanes per query group
constexpr int BLOCK = 256;
constexpr int Q = 2;                // queries per thread
constexpr int GROUPS = BLOCK / TQ;  // 32 groups/block
constexpr int QPB = GROUPS * Q;     // 64 queries/block
constexpr int S = M / TQ;           // 512 candidates per lane
}

// Shifted squared distance: |s|^2 - 2 p.s  (= d2 - |p|^2, order preserving).
// MUST be the identical op sequence everywhere (pass1 / argmin recompute / pass2).
__device__ __forceinline__ float d2of(const float4 s, float px, float py, float pz) {
  float dot = px * s.x;
  dot = fmaf(py, s.y, dot);
  dot = fmaf(pz, s.z, dot);
  return fmaf(-2.0f, dot, s.w);
}

// ascending compare-exchange on a[]
#define CEA(x, y) { float lo_ = fminf(a[x], a[y]); a[y] = fmaxf(a[x], a[y]); a[x] = lo_; }
// descending compare-exchange on L[] (R4-validated mountain-bitonic merge)
#define CED(x, y) { float hi_ = fmaxf(L[x], L[y]); L[y] = fminf(L[x], L[y]); L[x] = hi_; }

__global__ __launch_bounds__(BLOCK, 2) void voroloss_kernel(
    const float* __restrict__ points,    // [B, N, 3]
    const float* __restrict__ spoints,   // [B, M, 3]
    float* __restrict__ out)             // [B, N]
{
  __shared__ float4 s4[M];   // (x, y, z, |s|^2), 64 KiB

  const int blocks_per_batch = N / QPB;          // 256
  const int b = blockIdx.x / blocks_per_batch;
  const int tile = blockIdx.x % blocks_per_batch;
  const int tid = (int)threadIdx.x;
  const int h = tid & (TQ - 1);
  const int g = tid >> 3;

  const float* sp = spoints + (size_t)b * M * 3;
  for (int j = tid; j < M; j += BLOCK) {
    float x = sp[j * 3 + 0], y = sp[j * 3 + 1], z = sp[j * 3 + 2];
    s4[j] = make_float4(x, y, z, x * x + y * y + z * z);
  }
  __syncthreads();

  int n[Q];
  float px[Q], py[Q], pz[Q];
#pragma unroll
  for (int q = 0; q < Q; ++q) {
    n[q] = tile * QPB + q * GROUPS + g;
    px[q] = points[((size_t)b * N + n[q]) * 3 + 0];
    py[q] = points[((size_t)b * N + n[q]) * 3 + 1];
    pz[q] = points[((size_t)b * N + n[q]) * 3 + 2];
  }

  float bd[Q][K];
  float runmin[Q];
  int bbase[Q];
#pragma unroll
  for (int q = 0; q < Q; ++q) {
    runmin[q] = INFINITY;
    bbase[q] = 0;
#pragma unroll
    for (int t = 0; t < K; ++t) bd[q][t] = INFINITY;
  }

  // ---- Pass 1: branchless sort-network top-K. Each batch of 8 candidates is
  // sorted (19-CE Batcher), then merged into the sorted top-11 via the partner
  // trick + 17-CE descending bitonic merge. No data-dependent branches.
  for (int i0 = 0; i0 < S; i0 += 8) {
    float4 sv[8];
#pragma unroll
    for (int c = 0; c < 8; ++c) sv[c] = s4[(i0 + c) * TQ + h];
#pragma unroll
    for (int q = 0; q < Q; ++q) {
      float a[8];
#pragma unroll
      for (int c = 0; c < 8; ++c) a[c] = d2of(sv[c], px[q], py[q], pz[q]);
      // Batcher sort-8 ascending (19 CE)
      CEA(0,1) CEA(2,3) CEA(0,2) CEA(1,3) CEA(1,2)
      CEA(4,5) CEA(6,7) CEA(4,6) CEA(5,7) CEA(5,6)
      CEA(0,4) CEA(1,5) CEA(2,6) CEA(3,7)
      CEA(2,4) CEA(3,5)
      CEA(1,2) CEA(3,4) CEA(5,6)
      // batch argmin tracking (value + batch base; exact index recovered later)
      bool nm = a[0] < runmin[q];                // strict <: earliest batch wins ties
      runmin[q] = nm ? a[0] : runmin[q];
      bbase[q] = nm ? i0 : bbase[q];
      // 11 smallest of bd(asc,11) U a(asc,8): L[i] = min(bd[i], a[10-i]); i<3 -> bd[i]
      float L[K];
      L[0] = bd[q][0]; L[1] = bd[q][1]; L[2] = bd[q][2];
#pragma unroll
      for (int t = 3; t < K; ++t) L[t] = fminf(bd[q][t], a[10 - t]);
      // mountain-bitonic -> sorted descending (17 CE), then reverse
      CED(0,8) CED(1,9) CED(2,10)
      CED(0,4) CED(1,5) CED(2,6) CED(3,7)
      CED(0,2) CED(1,3) CED(4,6) CED(5,7)
      CED(0,1) CED(2,3) CED(4,5) CED(6,7)
      CED(8,10) CED(8,9)
#pragma unroll
      for (int t = 0; t < K; ++t) bd[q][t] = L[K - 1 - t];
    }
  }

  // Exact per-lane argmin index: recompute the winning batch (8 cands, once).
  int bidx[Q];
#pragma unroll
  for (int q = 0; q < Q; ++q) {
    int bi = 0x7fffffff;
#pragma unroll
    for (int c = 0; c < 8; ++c) {
      float4 s = s4[(bbase[q] + c) * TQ + h];
      float d = d2of(s, px[q], py[q], pz[q]);
      bool m = (d == runmin[q]) && (bi == 0x7fffffff);  // first match = lowest index
      bi = m ? ((bbase[q] + c) * TQ + h) : bi;
    }
    bidx[q] = bi;
  }

  // ---- 8-way cross-lane merge (xor 1,2,4), per query.
  float bd10[Q];
  int cand[Q];
#pragma unroll
  for (int q = 0; q < Q; ++q) {
    const float premin = runmin[q];
#pragma unroll
    for (int lvl = 1; lvl <= 4; lvl <<= 1) {
      float L[K];
#pragma unroll
      for (int t = 0; t < K; ++t) {
        float ob = __shfl_xor(bd[q][K - 1 - t], lvl);
        L[t] = fminf(bd[q][t], ob);   // K smallest of union; mountain-bitonic
      }
      CED(0,8) CED(1,9) CED(2,10)
      CED(0,4) CED(1,5) CED(2,6) CED(3,7)
      CED(0,2) CED(1,3) CED(4,6) CED(5,7)
      CED(0,1) CED(2,3) CED(4,5) CED(6,7)
      CED(8,10) CED(8,9)
#pragma unroll
      for (int t = 0; t < K; ++t) bd[q][t] = L[K - 1 - t];
    }
    bd10[q] = bd[q][K - 1];
    // argmin index, lowest index wins ties (top_k semantics)
    int cd = (premin == bd[q][0]) ? bidx[q] : 0x7fffffff;
#pragma unroll
    for (int lvl = 1; lvl <= 4; lvl <<= 1) {
      int oc = __shfl_xor(cd, lvl);
      cd = oc < cd ? oc : cd;
    }
    cand[q] = cd;
  }

  float ccx[Q], ccy[Q], ccz[Q], vx[Q], vy[Q], vz[Q];
#pragma unroll
  for (int q = 0; q < Q; ++q) {
    float4 cc = s4[cand[q]];
    ccx[q] = cc.x; ccy[q] = cc.y; ccz[q] = cc.z;
    vx[q] = px[q] - cc.x; vy[q] = py[q] - cc.y; vz[q] = pz[q] - cc.z;
  }

  // ---- Pass 2: branchless rescan. Neighbors are d2 <= bd10. The center itself
  // gives el2=0, tt=0 -> sq = 0*inf = NaN, which fminf (IEEE minNum) drops, so
  // no index test is needed. sq = (dot(v,e) - |e|^2/2)^2 / |e|^2.
  float best[Q];
#pragma unroll
  for (int q = 0; q < Q; ++q) best[q] = INFINITY;

  for (int i0 = 0; i0 < S; i0 += 8) {
    float4 sv[8];
#pragma unroll
    for (int c = 0; c < 8; ++c) sv[c] = s4[(i0 + c) * TQ + h];
#pragma unroll
    for (int q = 0; q < Q; ++q) {
#pragma unroll
      for (int c = 0; c < 8; ++c) {
        float d2 = d2of(sv[c], px[q], py[q], pz[q]);
        float ex = sv[c].x - ccx[q], ey = sv[c].y - ccy[q], ez = sv[c].z - ccz[q];
        float el2 = ex * ex;
        el2 = fmaf(ey, ey, el2);
        el2 = fmaf(ez, ez, el2);
        float dv = vx[q] * ex;
        dv = fmaf(vy[q], ey, dv);
        dv = fmaf(vz[q], ez, dv);
        float tt = fmaf(-0.5f, el2, dv);
        float sq = tt * tt * __builtin_amdgcn_rcpf(el2);
        float contrib = (d2 <= bd10[q]) ? sq : INFINITY;
        best[q] = fminf(best[q], contrib);
      }
    }
  }

#pragma unroll
  for (int q = 0; q < Q; ++q) {
#pragma unroll
    for (int lvl = 1; lvl <= 4; lvl <<= 1) {
      best[q] = fminf(best[q], __shfl_xor(best[q], lvl));
    }
    if (h == 0) out[(size_t)b * N + n[q]] = best[q];
  }
}

extern "C" void kernel_launch(void* const* d_in, const int* in_sizes, int n_in,
                              void* d_out, int out_size, void* d_ws, size_t ws_size,
                              hipStream_t stream) {
  const float* points = (const float*)d_in[0];
  const float* spoints = (const float*)d_in[1];
  float* out = (float*)d_out;
  (void)in_sizes; (void)n_in; (void)out_size; (void)d_ws; (void)ws_size;
  voroloss_kernel<<<dim3(B * (N / QPB)), dim3(BLOCK), 0, stream>>>(points, spoints, out);
}

// Round 6
// 128.877 us; speedup vs baseline: 5.1827x; 1.2799x over previous
//
#include <hip/hip_runtime.h>
#include <math.h>

namespace {
constexpr int B = 2;
constexpr int N = 16384;
constexpr int M = 4096;
constexpr int K = 11;
constexpr int TQ = 16;              // lanes per query group (within one wave)
constexpr int BLOCK = 512;          // 8 waves/block; 1 block/CU (LDS-limited)
constexpr int Q = 4;                // queries per thread
constexpr int GROUPS = BLOCK / TQ;  // 32 groups/block
constexpr int QPB = GROUPS * Q;     // 128 queries/block -> 256 blocks = 1/CU
constexpr int S = M / TQ;           // 256 candidates per lane
constexpr int CAP = 48;             // per-query collect buffer (3 per lane)
}

// Shifted squared distance: |s|^2 - 2 p.s (= d2 - |p|^2, order preserving).
// MUST be the identical op sequence in phases A/B/C for bit-exact agreement.
__device__ __forceinline__ float d2of(const float4 s, float px, float py, float pz) {
  float dot = px * s.x;
  dot = fmaf(py, s.y, dot);
  dot = fmaf(pz, s.z, dot);
  return fmaf(-2.0f, dot, s.w);
}

// descending compare-exchange (R4/R5-validated mountain-bitonic merge for n=11)
#define CED(x, y) { float hi_ = fmaxf(L[x], L[y]); L[y] = fminf(L[x], L[y]); L[x] = hi_; }

__global__ __launch_bounds__(BLOCK, 2) void voroloss_kernel(
    const float* __restrict__ points,    // [B, N, 3]
    const float* __restrict__ spoints,   // [B, M, 3]
    float* __restrict__ out)             // [B, N]
{
  __shared__ float4 s4[M];          // (x,y,z,|s|^2)  64 KiB
  __shared__ int cnt[QPB];          // collect counters
  __shared__ int2 buf[QPB][CAP];    // (idx, float_bits(d2))  48 KiB

  const int blocks_per_batch = N / QPB;        // 128
  const int b = blockIdx.x / blocks_per_batch;
  const int tile = blockIdx.x % blocks_per_batch;
  const int tid = (int)threadIdx.x;
  const int h = tid & (TQ - 1);
  const int g = tid >> 4;

  const float* sp = spoints + (size_t)b * M * 3;
  for (int j = tid; j < M; j += BLOCK) {
    float x = sp[j * 3 + 0], y = sp[j * 3 + 1], z = sp[j * 3 + 2];
    s4[j] = make_float4(x, y, z, x * x + y * y + z * z);
  }
  if (tid < QPB) cnt[tid] = 0;
  __syncthreads();

  int n[Q];
  float px[Q], py[Q], pz[Q];
#pragma unroll
  for (int q = 0; q < Q; ++q) {
    n[q] = tile * QPB + q * GROUPS + g;
    px[q] = points[((size_t)b * N + n[q]) * 3 + 0];
    py[q] = points[((size_t)b * N + n[q]) * 3 + 1];
    pz[q] = points[((size_t)b * N + n[q]) * 3 + 2];
  }

  // ---- Phase A: per-lane top-2 (branchless, 4 ops/cand) over strided subset.
  float t0[Q], t1[Q];
#pragma unroll
  for (int q = 0; q < Q; ++q) { t0[q] = INFINITY; t1[q] = INFINITY; }

  for (int i0 = 0; i0 < S; i0 += 8) {
    float4 sv[8];
#pragma unroll
    for (int c = 0; c < 8; ++c) sv[c] = s4[(i0 + c) * TQ + h];
#pragma unroll
    for (int q = 0; q < Q; ++q) {
#pragma unroll
      for (int c = 0; c < 8; ++c) {
        float d = d2of(sv[c], px[q], py[q], pz[q]);
        float lo = fminf(t0[q], d);
        float hi = fmaxf(t0[q], d);
        t0[q] = lo;
        t1[q] = fminf(t1[q], hi);
      }
    }
  }

  // ---- theta[q] = 11th smallest of the 32 per-lane top-2 values.
  // Provable upper bound on the true 11th smallest (11th of a sub-multiset),
  // so {d2 <= theta} contains the exact top-11. Expected |collect| ~ 13.
  float theta[Q];
#pragma unroll
  for (int q = 0; q < Q; ++q) {
    float bd[K];
    bd[0] = t0[q]; bd[1] = t1[q];
#pragma unroll
    for (int t = 2; t < K; ++t) bd[t] = INFINITY;
#pragma unroll
    for (int lvl = 1; lvl <= 8; lvl <<= 1) {
      float L[K];
#pragma unroll
      for (int t = 0; t < K; ++t) {
        float ob = __shfl_xor(bd[K - 1 - t], lvl);
        L[t] = fminf(bd[t], ob);   // 11 smallest of union; mountain-bitonic
      }
      CED(0,8) CED(1,9) CED(2,10)
      CED(0,4) CED(1,5) CED(2,6) CED(3,7)
      CED(0,2) CED(1,3) CED(4,6) CED(5,7)
      CED(0,1) CED(2,3) CED(4,5) CED(6,7)
      CED(8,10) CED(8,9)
#pragma unroll
      for (int t = 0; t < K; ++t) bd[t] = L[K - 1 - t];
    }
    theta[q] = bd[K - 1];
  }

  // ---- Phase B: rescan, collect qualifying (idx,d2) into per-query buffer.
  // All pushes for a query come from its own 16 lanes (same wave): no barrier.
  for (int i0 = 0; i0 < S; i0 += 8) {
    float4 sv[8];
#pragma unroll
    for (int c = 0; c < 8; ++c) sv[c] = s4[(i0 + c) * TQ + h];
#pragma unroll
    for (int q = 0; q < Q; ++q) {
      float d2v[8];
#pragma unroll
      for (int c = 0; c < 8; ++c) d2v[c] = d2of(sv[c], px[q], py[q], pz[q]);
      float m01 = fminf(d2v[0], d2v[1]), m23 = fminf(d2v[2], d2v[3]);
      float m45 = fminf(d2v[4], d2v[5]), m67 = fminf(d2v[6], d2v[7]);
      float m = fminf(fminf(m01, m23), fminf(m45, m67));
      if (m <= theta[q]) {
        const int qq = q * GROUPS + g;
#pragma unroll
        for (int c = 0; c < 8; ++c) {
          if (d2v[c] <= theta[q]) {
            int p = atomicAdd(&cnt[qq], 1);
            if (p < CAP) buf[qq][p] = make_int2((i0 + c) * TQ + h,
                                                __float_as_int(d2v[c]));
          }
        }
      }
    }
  }

  // ---- Phase C: exact selection among collected (lex (d2, idx) = stable top_k).
#pragma unroll
  for (int q = 0; q < Q; ++q) {
    const int qq = q * GROUPS + g;
    int c = cnt[qq];
    c = c < CAP ? c : CAP;

    // this lane's up-to-3 entries
    float ed2[3];
    int eidx[3];
#pragma unroll
    for (int r = 0; r < 3; ++r) {
      int e = h + r * TQ;
      bool v = e < c;
      int2 pe = buf[qq][v ? e : 0];
      ed2[r] = v ? __int_as_float(pe.y) : INFINITY;
      eidx[r] = v ? pe.x : 0x7fffffff;
    }

    // lex ranks: rank = #{f : (d2_f, idx_f) < (d2_e, idx_e)}  (all distinct)
    int rank[3] = {0, 0, 0};
    for (int f = 0; f < c; ++f) {
      int2 pf = buf[qq][f];
      float df = __int_as_float(pf.y);
      int jf = pf.x;
#pragma unroll
      for (int r = 0; r < 3; ++r) {
        bool less = (df < ed2[r]) || (df == ed2[r] && jf < eidx[r]);
        rank[r] += less ? 1 : 0;
      }
    }

    // center = lex-min (rank 0): group shfl reduction
    float cd = ed2[0]; int ci = eidx[0];
#pragma unroll
    for (int r = 1; r < 3; ++r) {
      bool take = (ed2[r] < cd) || (ed2[r] == cd && eidx[r] < ci);
      cd = take ? ed2[r] : cd;
      ci = take ? eidx[r] : ci;
    }
#pragma unroll
    for (int lvl = 1; lvl <= 8; lvl <<= 1) {
      float od = __shfl_xor(cd, lvl);
      int oi = __shfl_xor(ci, lvl);
      bool take = (od < cd) || (od == cd && oi < ci);
      cd = take ? od : cd;
      ci = take ? oi : ci;
    }
    float4 cc = s4[ci];
    float vx = px[q] - cc.x, vy = py[q] - cc.y, vz = pz[q] - cc.z;

    // edges = ranks 1..10: sq = (dot(v,e) - |e|^2/2)^2 / |e|^2
    float best = INFINITY;
#pragma unroll
    for (int r = 0; r < 3; ++r) {
      bool isedge = (rank[r] >= 1) && (rank[r] <= 10);
      float4 s = s4[isedge ? eidx[r] : 0];
      float ex = s.x - cc.x, ey = s.y - cc.y, ez = s.z - cc.z;
      float el2 = ex * ex;
      el2 = fmaf(ey, ey, el2);
      el2 = fmaf(ez, ez, el2);
      float dv = vx * ex;
      dv = fmaf(vy, ey, dv);
      dv = fmaf(vz, ez, dv);
      float tt = fmaf(-0.5f, el2, dv);
      float sq = tt * tt * __builtin_amdgcn_rcpf(el2);
      best = fminf(best, isedge ? sq : INFINITY);
    }
#pragma unroll
    for (int lvl = 1; lvl <= 8; lvl <<= 1) {
      best = fminf(best, __shfl_xor(best, lvl));
    }
    if (h == 0) out[(size_t)b * N + n[q]] = best;
  }
}

extern "C" void kernel_launch(void* const* d_in, const int* in_sizes, int n_in,
                              void* d_out, int out_size, void* d_ws, size_t ws_size,
                              hipStream_t stream) {
  const float* points = (const float*)d_in[0];
  const float* spoints = (const float*)d_in[1];
  float* out = (float*)d_out;
  (void)in_sizes; (void)n_in; (void)out_size; (void)d_ws; (void)ws_size;
  voroloss_kernel<<<dim3(B * (N / QPB)), dim3(BLOCK), 0, stream>>>(points, spoints, out);
}

// Round 7
// 101.846 us; speedup vs baseline: 6.5582x; 1.2654x over previous
//
#include <hip/hip_runtime.h>
#include <math.h>

namespace {
constexpr int B = 2;
constexpr int N = 16384;
constexpr int M = 4096;
constexpr int K = 11;
constexpr int TQ = 32;              // lanes per query group (half-wave)
constexpr int BLOCK = 512;          // 8 waves; 2 blocks/CU (LDS 72.3 KiB) -> 4 waves/SIMD
constexpr int Q = 4;                // queries per thread
constexpr int GROUPS = BLOCK / TQ;  // 16 groups/block
constexpr int QPB = GROUPS * Q;     // 64 queries/block -> 512 blocks = 2/CU
constexpr int S = M / TQ;           // 128 candidates per lane
constexpr int CAP = 64;             // collect capacity (2 slots per lane)
}

// Shifted squared distance: |s|^2 - 2 p.s  (order preserving vs true d2).
// Pure 3-fmaf chain with precomputed (-2px,-2py,-2pz). MUST be the identical
// op sequence in phases A/B/C for bit-exact threshold agreement.
__device__ __forceinline__ float d2of(const float4 s, float m2x, float m2y, float m2z) {
  return fmaf(m2x, s.x, fmaf(m2y, s.y, fmaf(m2z, s.z, s.w)));
}

__global__ __launch_bounds__(BLOCK, 4) void voroloss_kernel(
    const float* __restrict__ points,    // [B, N, 3]
    const float* __restrict__ spoints,   // [B, M, 3]
    float* __restrict__ out)             // [B, N]
{
  __shared__ float4 s4[M];                        // (x,y,z,|s|^2)  64 KiB
  __shared__ unsigned short buf[QPB][CAP];        // candidate idx   8 KiB
  __shared__ int cnt[QPB];

  const int blocks_per_batch = N / QPB;           // 256
  const int b = blockIdx.x / blocks_per_batch;
  const int tile = blockIdx.x % blocks_per_batch;
  const int tid = (int)threadIdx.x;
  const int h = tid & (TQ - 1);   // lane within group
  const int g = tid >> 5;         // group id (0..15)
  const int wl = tid & 63;        // lane in wave
  const int gb = wl & 32;         // group base lane within wave

  const float* sp = spoints + (size_t)b * M * 3;
  for (int j = tid; j < M; j += BLOCK) {
    float x = sp[j * 3 + 0], y = sp[j * 3 + 1], z = sp[j * 3 + 2];
    s4[j] = make_float4(x, y, z, x * x + y * y + z * z);
  }
  if (tid < QPB) cnt[tid] = 0;
  __syncthreads();

  int n[Q];
  float m2x[Q], m2y[Q], m2z[Q], px[Q], py[Q], pz[Q];
#pragma unroll
  for (int q = 0; q < Q; ++q) {
    n[q] = tile * QPB + q * GROUPS + g;
    px[q] = points[((size_t)b * N + n[q]) * 3 + 0];
    py[q] = points[((size_t)b * N + n[q]) * 3 + 1];
    pz[q] = points[((size_t)b * N + n[q]) * 3 + 2];
    m2x[q] = -2.0f * px[q];
    m2y[q] = -2.0f * py[q];
    m2z[q] = -2.0f * pz[q];
  }

  // ---- Phase A: per-lane MIN over strided subset (4 ops/cand/q).
  float t0[Q];
#pragma unroll
  for (int q = 0; q < Q; ++q) t0[q] = INFINITY;

  for (int i0 = 0; i0 < S; i0 += 8) {
    float4 sv[8];
#pragma unroll
    for (int c = 0; c < 8; ++c) sv[c] = s4[(i0 + c) * TQ + h];
#pragma unroll
    for (int q = 0; q < Q; ++q) {
#pragma unroll
      for (int c = 0; c < 8; ++c) {
        t0[q] = fminf(t0[q], d2of(sv[c], m2x[q], m2y[q], m2z[q]));
      }
    }
  }

  // ---- theta[q] = 11th smallest of the 32 lane minima (cross-lane bitonic
  // sort-32 via shfl_xor; xor<=16 stays inside the 32-lane group). Provable
  // upper bound on the true 11th smallest: order stat of a sub-multiset.
  float theta[Q];
#pragma unroll
  for (int q = 0; q < Q; ++q) {
    float x = t0[q];
#pragma unroll
    for (int k = 2; k <= 32; k <<= 1) {
#pragma unroll
      for (int j = 16; j > 0; j >>= 1) {
        if (j < k) {
          float o = __shfl_xor(x, j);
          bool up = (h & k) == 0;            // ascending block (k=32: all up)
          bool lower = (h & j) == 0;
          bool keepmin = (lower == up);
          x = keepmin ? fminf(x, o) : fmaxf(x, o);
        }
      }
    }
    theta[q] = __shfl(x, gb + 10, 64);       // group-local rank 10 = 11th smallest
  }

  // ---- Phase B: rescan, push qualifying indices (d2 <= theta) into the
  // per-query buffer. All pushes come from the query's own 32 lanes (one
  // wave): no barrier needed. Expected count ~14, CAP=64 guard.
  for (int i0 = 0; i0 < S; i0 += 8) {
    float4 sv[8];
#pragma unroll
    for (int c = 0; c < 8; ++c) sv[c] = s4[(i0 + c) * TQ + h];
#pragma unroll
    for (int q = 0; q < Q; ++q) {
      const int qq = q * GROUPS + g;
#pragma unroll
      for (int c = 0; c < 8; ++c) {
        float d = d2of(sv[c], m2x[q], m2y[q], m2z[q]);
        if (d <= theta[q]) {
          int p = atomicAdd(&cnt[qq], 1);
          if (p < CAP) buf[qq][p] = (unsigned short)((i0 + c) * TQ + h);
        }
      }
    }
  }

  // ---- Phase C: exact selection among collected (lex (d2, idx) = stable
  // top_k). Each lane owns slots h and h+32; d2 recomputed (bit-exact d2of).
#pragma unroll
  for (int q = 0; q < Q; ++q) {
    const int qq = q * GROUPS + g;
    int c = cnt[qq];
    c = c < CAP ? c : CAP;

    float ed2[2];
    int eidx[2];
#pragma unroll
    for (int r = 0; r < 2; ++r) {
      int e = h + r * TQ;
      bool v = e < c;
      int idx = v ? (int)buf[qq][e] : 0;
      float4 s = s4[idx];
      ed2[r] = v ? d2of(s, m2x[q], m2y[q], m2z[q]) : INFINITY;
      eidx[r] = v ? idx : 0x7fffffff;
    }

    // lex ranks (all (d2,idx) distinct). Entry f lives in slot f>>5 of lane f&31.
    int rank[2] = {0, 0};
    int c1 = c < TQ ? c : TQ;
    for (int f = 0; f < c1; ++f) {
      float df = __shfl(ed2[0], gb + f, 64);
      int jf = __shfl(eidx[0], gb + f, 64);
#pragma unroll
      for (int r = 0; r < 2; ++r) {
        bool less = (df < ed2[r]) || (df == ed2[r] && jf < eidx[r]);
        rank[r] += less ? 1 : 0;
      }
    }
    for (int f = TQ; f < c; ++f) {
      float df = __shfl(ed2[1], gb + (f - TQ), 64);
      int jf = __shfl(eidx[1], gb + (f - TQ), 64);
#pragma unroll
      for (int r = 0; r < 2; ++r) {
        bool less = (df < ed2[r]) || (df == ed2[r] && jf < eidx[r]);
        rank[r] += less ? 1 : 0;
      }
    }

    // center = lex-min (rank 0)
    float cd = ed2[0]; int ci = eidx[0];
    {
      bool take = (ed2[1] < cd) || (ed2[1] == cd && eidx[1] < ci);
      cd = take ? ed2[1] : cd;
      ci = take ? eidx[1] : ci;
    }
#pragma unroll
    for (int lvl = 1; lvl <= 16; lvl <<= 1) {
      float od = __shfl_xor(cd, lvl);
      int oi = __shfl_xor(ci, lvl);
      bool take = (od < cd) || (od == cd && oi < ci);
      cd = take ? od : cd;
      ci = take ? oi : ci;
    }
    float4 cc = s4[ci];
    float vx = px[q] - cc.x, vy = py[q] - cc.y, vz = pz[q] - cc.z;

    // edges = ranks 1..10 (invalid slots have rank >= c >= 11 -> excluded).
    // sq = (dot(v,e) - |e|^2/2)^2 / |e|^2
    float best = INFINITY;
#pragma unroll
    for (int r = 0; r < 2; ++r) {
      bool isedge = (rank[r] >= 1) && (rank[r] <= 10);
      float4 s = s4[isedge ? eidx[r] : 0];
      float ex = s.x - cc.x, ey = s.y - cc.y, ez = s.z - cc.z;
      float el2 = ex * ex;
      el2 = fmaf(ey, ey, el2);
      el2 = fmaf(ez, ez, el2);
      float dv = vx * ex;
      dv = fmaf(vy, ey, dv);
      dv = fmaf(vz, ez, dv);
      float tt = fmaf(-0.5f, el2, dv);
      float sq = tt * tt * __builtin_amdgcn_rcpf(el2);
      best = fminf(best, isedge ? sq : INFINITY);
    }
#pragma unroll
    for (int lvl = 1; lvl <= 16; lvl <<= 1) {
      best = fminf(best, __shfl_xor(best, lvl));
    }
    if (h == 0) out[(size_t)b * N + n[q]] = best;
  }
}

extern "C" void kernel_launch(void* const* d_in, const int* in_sizes, int n_in,
                              void* d_out, int out_size, void* d_ws, size_t ws_size,
                              hipStream_t stream) {
  const float* points = (const float*)d_in[0];
  const float* spoints = (const float*)d_in[1];
  float* out = (float*)d_out;
  (void)in_sizes; (void)n_in; (void)out_size; (void)d_ws; (void)ws_size;
  voroloss_kernel<<<dim3(B * (N / QPB)), dim3(BLOCK), 0, stream>>>(points, spoints, out);
}